// Round 13
// baseline (175.400 us; speedup 1.0000x reference)
//
#include <hip/hip_runtime.h>
#include <math.h>

#define NUM_IN 1024
#define TILE_R 16
#define NB_MAX 256

using bf16x8 = __attribute__((ext_vector_type(8))) short;
using f32x4  = __attribute__((ext_vector_type(4))) float;

__device__ __forceinline__ unsigned int f2bf1(float f) {
  unsigned int u = __float_as_uint(f);
  return (u + 0x7fffu + ((u >> 16) & 1u)) >> 16;   // RNE f32 -> bf16
}
__device__ __forceinline__ unsigned int pk2(float a, float b) {
  return f2bf1(a) | (f2bf1(b) << 16);
}
__device__ __forceinline__ float bflo(unsigned int w) { return __uint_as_float(w << 16); }
__device__ __forceinline__ float bfhi(unsigned int w) { return __uint_as_float(w & 0xffff0000u); }

// barrier draining LDS ops only — global loads stay in flight
#define BARX() do { \
  __builtin_amdgcn_sched_barrier(0); \
  asm volatile("s_waitcnt lgkmcnt(0)" ::: "memory"); \
  __builtin_amdgcn_s_barrier(); \
  __builtin_amdgcn_sched_barrier(0); \
} while (0)

#define WAIT_VM(n) do { \
  __builtin_amdgcn_sched_barrier(0); \
  asm volatile("s_waitcnt vmcnt(" #n ")" ::: "memory"); \
  __builtin_amdgcn_sched_barrier(0); \
} while (0)

// 256 blocks x 512 threads (8 waves). Wave w = K-slice (128 cols); lane: row
// l15, k-group kg. v13: LINE-COALESCED loads — per row each instruction reads
// a contiguous 64B (kg*16), so every load touches 16 fully-consumed cachelines
// (copy-kernel request efficiency). The MFMA k<->column bijection is adjusted
// to match (A and B share the map; weights gathered accordingly at startup).
// col(s,i) = w*128 + s*32 + (i>>2)*16 + kg*4 + (i&3).
__global__ __launch_bounds__(512, 1) void ga_main(
    const float* __restrict__ x,
    const float* __restrict__ Vw, const float* __restrict__ Uw,
    const float* __restrict__ Vb, const float* __restrict__ Ub,
    const float* __restrict__ ww, const float* __restrict__ wb,
    float* __restrict__ wsAcc, float* __restrict__ wsM, float* __restrict__ wsS,
    int nb, int nTiles)
{
  // [buf][kq][row][o ^ ((row>>2 & 1)<<4)] : act reads stride-1 (free),
  // MFMA writes 2-way (free). 64 KB total.
  __shared__ __align__(16) float prered[2][8][16][64];
  __shared__ __align__(16) float lgs[2][16];

  const int tid = threadIdx.x;
  const int b   = blockIdx.x;
  const int w   = tid >> 6;        // K-slice 0..7
  const int l   = tid & 63;
  const int l15 = l & 15;          // x-row within tile / o-sub
  const int kg  = l >> 4;          // 0..3
  const int h   = tid & 31;
  const int rr  = tid >> 5;        // act row 0..15
  const int xsw = (kg & 1) << 4;          // write-side xor (kg = row>>2)
  const int xsr = ((rr >> 2) & 1) << 4;   // read-side xor

  const float vbh = Vb[h], ubh = Ub[h], wwh = ww[h];
  const float wb0 = wb[0];

  // ---- weights: B-frags for (all nt, this w): 16 x uint4 = 64 VGPR ----
  // gathered under the v13 k-map: chunk s regs i=0..3 -> cols k0..k0+3,
  // i=4..7 -> cols k0+16..k0+19, with k0 = w*128 + s*32 + kg*4
  uint4 bfr[4][4];
  {
    #pragma unroll
    for (int nt = 0; nt < 4; ++nt) {
      const int o = (nt << 4) + l15;
      const float* Wr = (o < 32) ? (Vw + (size_t)o * NUM_IN) : (Uw + (size_t)(o - 32) * NUM_IN);
      #pragma unroll
      for (int s = 0; s < 4; ++s) {
        const int k0 = (w << 7) + (s << 5) + (kg << 2);
        const float4 a = *reinterpret_cast<const float4*>(Wr + k0);
        const float4 c = *reinterpret_cast<const float4*>(Wr + k0 + 16);
        uint4 v;
        v.x = pk2(a.x, a.y); v.y = pk2(a.z, a.w);
        v.z = pk2(c.x, c.y); v.w = pk2(c.z, c.w);
        bfr[nt][s] = v;
      }
    }
    #pragma unroll
    for (int nt = 0; nt < 4; ++nt)
      #pragma unroll
      for (int s = 0; s < 4; ++s)
        asm volatile("" : "+v"(bfr[nt][s].x), "+v"(bfr[nt][s].y),
                          "+v"(bfr[nt][s].z), "+v"(bfr[nt][s].w));
  }

  const char* xb8 = (const char*)x;
  const int inRow = (w << 9) + (kg << 4);      // byte offset within a 4 KB row

  float4 sA0[4], sB0[4], sA1[4], sB1[4];       // 64 VGPR: two staging sets
  uint4  xfA[4], xfB[4];                       // 32 VGPR: bf16 frags, 2 tiles live

  // per instruction: 16 rows x contiguous 64B -> 16 fully-consumed lines
  #define ISSUE_SET(sa, sb, Tt) do { \
    __builtin_amdgcn_sched_barrier(0); \
    const int Tc_ = ((Tt) < nTiles) ? (Tt) : (nTiles - 1); \
    const char* base_ = xb8 + ((size_t)Tc_ * TILE_R + l15) * 4096 + inRow; \
    sa[0] = *reinterpret_cast<const float4*>(base_      );  sb[0] = *reinterpret_cast<const float4*>(base_ +  64); \
    sa[1] = *reinterpret_cast<const float4*>(base_ + 128);  sb[1] = *reinterpret_cast<const float4*>(base_ + 192); \
    sa[2] = *reinterpret_cast<const float4*>(base_ + 256);  sb[2] = *reinterpret_cast<const float4*>(base_ + 320); \
    sa[3] = *reinterpret_cast<const float4*>(base_ + 384);  sb[3] = *reinterpret_cast<const float4*>(base_ + 448); \
    __builtin_amdgcn_sched_barrier(0); \
  } while (0)

  #define PACK_SET(dst, sa, sb) do { \
    _Pragma("unroll") \
    for (int s = 0; s < 4; ++s) { \
      dst[s].x = pk2(sa[s].x, sa[s].y); dst[s].y = pk2(sa[s].z, sa[s].w); \
      dst[s].z = pk2(sb[s].x, sb[s].y); dst[s].w = pk2(sb[s].z, sb[s].w); \
    } \
    _Pragma("unroll") \
    for (int s = 0; s < 4; ++s) \
      asm volatile("" : "+v"(dst[s].x), "+v"(dst[s].y), "+v"(dst[s].z), "+v"(dst[s].w)); \
  } while (0)

  float M = -INFINITY, S = 0.f;
  float acc[4][8];
  #pragma unroll
  for (int s = 0; s < 4; ++s)
    #pragma unroll
    for (int i = 0; i < 8; ++i) acc[s][i] = 0.f;

  // P1: 16 MFMAs from registers -> prered[pb]
  #define MFMA_PHASE(xfS, pb) do { \
    f32x4 a4[4] = {{0.f,0.f,0.f,0.f},{0.f,0.f,0.f,0.f},{0.f,0.f,0.f,0.f},{0.f,0.f,0.f,0.f}}; \
    _Pragma("unroll") \
    for (int s = 0; s < 4; ++s) { \
      const bf16x8 af = __builtin_bit_cast(bf16x8, xfS[s]); \
      _Pragma("unroll") \
      for (int nt = 0; nt < 4; ++nt) \
        a4[nt] = __builtin_amdgcn_mfma_f32_16x16x32_bf16( \
            af, __builtin_bit_cast(bf16x8, bfr[nt][s]), a4[nt], 0, 0, 0); \
    } \
    _Pragma("unroll") \
    for (int nt = 0; nt < 4; ++nt) \
      _Pragma("unroll") \
      for (int r = 0; r < 4; ++r) \
        prered[pb][w][(kg << 2) + r][((nt << 4) + l15) ^ xsw] = a4[nt][r]; \
  } while (0)

  // act(T): 512 threads = 16 rows x 32 h -> lgs[lb]
  #define ACT_PHASE(pb, lb) do { \
    float pv = vbh, pu = ubh; \
    _Pragma("unroll") \
    for (int q = 0; q < 8; ++q) { \
      pv += prered[pb][q][rr][h ^ xsr]; \
      pu += prered[pb][q][rr][(h + 32) ^ xsr]; \
    } \
    const float ev = __expf(2.f * pv); \
    const float av = (ev - 1.f) * __builtin_amdgcn_rcpf(ev + 1.f); \
    const float au = __builtin_amdgcn_rcpf(1.f + __expf(-pu)); \
    float g = av * au * wwh; \
    g += __shfl_xor(g, 1); \
    g += __shfl_xor(g, 2); \
    g += __shfl_xor(g, 4); \
    g += __shfl_xor(g, 8); \
    g += __shfl_xor(g, 16); \
    if (h == 0) lgs[lb][rr] = g + wb0; \
  } while (0)

  // softmax + weighted accumulation for the tile whose frags are in xfS
  #define ACC_PHASE(xfS, lb) do { \
    const float lf = lgs[lb][l15]; \
    float mc = lf; \
    mc = fmaxf(mc, __shfl_xor(mc, 1)); \
    mc = fmaxf(mc, __shfl_xor(mc, 2)); \
    mc = fmaxf(mc, __shfl_xor(mc, 4)); \
    mc = fmaxf(mc, __shfl_xor(mc, 8)); \
    if (mc > M) { \
      const float scale = __expf(M - mc); \
      S *= scale; \
      _Pragma("unroll") \
      for (int s = 0; s < 4; ++s) \
        _Pragma("unroll") \
        for (int i = 0; i < 8; ++i) acc[s][i] *= scale; \
      M = mc; \
    } \
    const float p = __expf(lf - M); \
    S += p; \
    _Pragma("unroll") \
    for (int s = 0; s < 4; ++s) { \
      acc[s][0] = fmaf(p, bflo(xfS[s].x), acc[s][0]); \
      acc[s][1] = fmaf(p, bfhi(xfS[s].x), acc[s][1]); \
      acc[s][2] = fmaf(p, bflo(xfS[s].y), acc[s][2]); \
      acc[s][3] = fmaf(p, bfhi(xfS[s].y), acc[s][3]); \
      acc[s][4] = fmaf(p, bflo(xfS[s].z), acc[s][4]); \
      acc[s][5] = fmaf(p, bfhi(xfS[s].z), acc[s][5]); \
      acc[s][6] = fmaf(p, bflo(xfS[s].w), acc[s][6]); \
      acc[s][7] = fmaf(p, bfhi(xfS[s].w), acc[s][7]); \
    } \
  } while (0)

  // ---- prologue + peeled iteration 0 (tile b, parity 0; no acc yet) ----
  ISSUE_SET(sA0, sB0, b);
  WAIT_VM(0);
  PACK_SET(xfA, sA0, sB0);             // xfA = T0
  ISSUE_SET(sA0, sB0, b + nb);         // T1
  ISSUE_SET(sA1, sB1, b + 2 * nb);     // T2
  MFMA_PHASE(xfA, 0);
  BARX();
  ACT_PHASE(0, 0);
  WAIT_VM(8);
  PACK_SET(xfB, sA0, sB0);             // xfB = T1
  ISSUE_SET(sA0, sB0, b + 3 * nb);     // T3

  int Tk = b + nb;
  int lastPar = 0;
  if (Tk < nTiles) {
    while (true) {
      // body ODD: tile Tk (parity 1): MFMA(xfB); act->lgs[1]; acc(prev, xfA, lgs[0])
      MFMA_PHASE(xfB, 1);
      BARX();
      ACT_PHASE(1, 1);
      ACC_PHASE(xfA, 0);
      WAIT_VM(8);
      PACK_SET(xfA, sA1, sB1);         // next tile (Tk+1)
      ISSUE_SET(sA1, sB1, Tk + 3 * nb);
      Tk += nb;
      if (Tk >= nTiles) { lastPar = 1; break; }

      // body EVEN: tile Tk (parity 0): MFMA(xfA); act->lgs[0]; acc(prev, xfB, lgs[1])
      MFMA_PHASE(xfA, 0);
      BARX();
      ACT_PHASE(0, 0);
      ACC_PHASE(xfB, 1);
      WAIT_VM(8);
      PACK_SET(xfB, sA0, sB0);
      ISSUE_SET(sA0, sB0, Tk + 3 * nb);
      Tk += nb;
      if (Tk >= nTiles) { lastPar = 0; break; }
    }
  }
  // drain: acc for the last tile (its act ran in the final body)
  BARX();
  if (lastPar) { ACC_PHASE(xfB, 1); } else { ACC_PHASE(xfA, 0); }

  // ---- epilogue: butterfly-sum acc & S over the 16-lane row group ----
  #pragma unroll
  for (int d = 1; d < 16; d <<= 1) {
    #pragma unroll
    for (int s = 0; s < 4; ++s)
      #pragma unroll
      for (int i = 0; i < 8; ++i) acc[s][i] += __shfl_xor(acc[s][i], d);
    S += __shfl_xor(S, d);
  }
  if (l15 == 0) {   // lane (w,kg): acc[s][0..3] -> cols k0..k0+3, [4..7] -> k0+16..+19
    #pragma unroll
    for (int s = 0; s < 4; ++s) {
      float* dst = &wsAcc[(size_t)b * NUM_IN + (w << 7) + (s << 5) + (kg << 2)];
      *reinterpret_cast<float4*>(dst)      = make_float4(acc[s][0], acc[s][1], acc[s][2], acc[s][3]);
      *reinterpret_cast<float4*>(dst + 16) = make_float4(acc[s][4], acc[s][5], acc[s][6], acc[s][7]);
    }
  }
  if (tid == 0) { wsM[b] = M; wsS[b] = S; }
}

// stage 1: global max M, weights wg_i = exp(M_i - M), total S -> wsT[0]=S
__global__ void ga_reduceMS(const float* __restrict__ wsM, const float* __restrict__ wsS,
                            float* __restrict__ wsW, float* __restrict__ wsT, int nb)
{
  __shared__ float sm[8], ss[8];
  const int t = threadIdx.x;   // 512
  float m = (t < nb) ? wsM[t] : -INFINITY;
  float mm = m;
  #pragma unroll
  for (int d = 1; d < 64; d <<= 1) mm = fmaxf(mm, __shfl_xor(mm, d));
  if ((t & 63) == 0) sm[t >> 6] = mm;
  __syncthreads();
  const float M = fmaxf(fmaxf(fmaxf(sm[0], sm[1]), fmaxf(sm[2], sm[3])),
                        fmaxf(fmaxf(sm[4], sm[5]), fmaxf(sm[6], sm[7])));
  const float wg = (t < nb) ? __expf(m - M) : 0.f;
  if (t < nb) wsW[t] = wg;
  float s = wg * ((t < nb) ? wsS[t] : 0.f);
  #pragma unroll
  for (int d = 1; d < 64; d <<= 1) s += __shfl_xor(s, d);
  if ((t & 63) == 0) ss[t >> 6] = s;
  __syncthreads();
  if (t == 0) {
    float St = 0.f;
    #pragma unroll
    for (int k = 0; k < 8; ++k) St += ss[k];
    wsT[0] = St;
  }
}

// stage 2: out[col] = (sum_i wg_i * wsAcc[i][col]) / S. 32 blocks x 32 cols.
__global__ void ga_combine(const float* __restrict__ wsAcc, const float* __restrict__ wsW,
                           const float* __restrict__ wsT, float* __restrict__ out, int nb)
{
  __shared__ float red[8][32];
  const int t = threadIdx.x;                    // 256
  const int col = (blockIdx.x << 5) + (t & 31);
  const int seg = t >> 5;                       // 0..7
  float s = 0.f;
  for (int ii = 0; ii < 64; ++ii) {
    const int i = (seg << 6) + ii;
    if (i < nb) s = fmaf(wsW[i], wsAcc[(size_t)i * NUM_IN + col], s);
  }
  red[seg][t & 31] = s;
  __syncthreads();
  if (seg == 0) {
    float tot = 0.f;
    #pragma unroll
    for (int k = 0; k < 8; ++k) tot += red[k][t];
    out[col] = tot / wsT[0];
  }
}

extern "C" void kernel_launch(void* const* d_in, const int* in_sizes, int n_in,
                              void* d_out, int out_size, void* d_ws, size_t ws_size,
                              hipStream_t stream)
{
  const float* x  = (const float*)d_in[0];
  const float* Vw = (const float*)d_in[1];
  const float* Vb = (const float*)d_in[2];
  const float* Uw = (const float*)d_in[3];
  const float* Ub = (const float*)d_in[4];
  const float* ww = (const float*)d_in[5];
  const float* wb = (const float*)d_in[6];
  float* out = (float*)d_out;

  const int Nrows  = in_sizes[0] / NUM_IN;   // 200000
  const int nTiles = Nrows / TILE_R;         // 12500

  const size_t per = (size_t)NUM_IN * 4 + 16;
  int nb = (int)((ws_size - 64) / per);
  if (nb > NB_MAX)  nb = NB_MAX;
  if (nb > nTiles)  nb = nTiles;
  if (nb < 1)       nb = 1;

  float* wsAcc = (float*)d_ws;
  float* wsM   = wsAcc + (size_t)nb * NUM_IN;
  float* wsS   = wsM + nb;
  float* wsW   = wsS + nb;
  float* wsT   = wsW + nb;

  ga_main<<<nb, 512, 0, stream>>>(x, Vw, Uw, Vb, Ub, ww, wb, wsAcc, wsM, wsS, nb, nTiles);
  ga_reduceMS<<<1, 512, 0, stream>>>(wsM, wsS, wsW, wsT, nb);
  ga_combine<<<32, 256, 0, stream>>>(wsAcc, wsW, wsT, out, nb);
}

// Round 14
// 174.339 us; speedup vs baseline: 1.0061x; 1.0061x over previous
//
#include <hip/hip_runtime.h>
#include <math.h>

#define NUM_IN 1024
#define TILE_R 16
#define NB_MAX 256

using bf16x8 = __attribute__((ext_vector_type(8))) short;
using f32x4  = __attribute__((ext_vector_type(4))) float;

__device__ __forceinline__ unsigned int f2bf1(float f) {
  unsigned int u = __float_as_uint(f);
  return (u + 0x7fffu + ((u >> 16) & 1u)) >> 16;   // RNE f32 -> bf16
}
__device__ __forceinline__ unsigned int pk2(float a, float b) {
  return f2bf1(a) | (f2bf1(b) << 16);
}
__device__ __forceinline__ float bflo(unsigned int w) { return __uint_as_float(w << 16); }
__device__ __forceinline__ float bfhi(unsigned int w) { return __uint_as_float(w & 0xffff0000u); }

// barrier draining LDS ops only — global loads stay in flight
#define BARX() do { \
  __builtin_amdgcn_sched_barrier(0); \
  asm volatile("s_waitcnt lgkmcnt(0)" ::: "memory"); \
  __builtin_amdgcn_s_barrier(); \
  __builtin_amdgcn_sched_barrier(0); \
} while (0)

#define WAIT_VM(n) do { \
  __builtin_amdgcn_sched_barrier(0); \
  asm volatile("s_waitcnt vmcnt(" #n ")" ::: "memory"); \
  __builtin_amdgcn_sched_barrier(0); \
} while (0)

// 256 blocks x 512 threads (8 waves). Wave w = K-slice (128 cols); lane: row
// l15, k-group kg. Line-coalesced loads (per row contiguous 64B), MFMA k-map
// matched on A and B. A-frags + Phase-B weighted sum register-resident.
// 2-deep staging, counted vmcnt(8); 1 barrier per iteration.
// col(s,i) = w*128 + s*32 + (i>>2)*16 + kg*4 + (i&3).
__global__ __launch_bounds__(512, 1) void ga_main(
    const float* __restrict__ x,
    const float* __restrict__ Vw, const float* __restrict__ Uw,
    const float* __restrict__ Vb, const float* __restrict__ Ub,
    const float* __restrict__ ww, const float* __restrict__ wb,
    float* __restrict__ wsAcc, float* __restrict__ wsM, float* __restrict__ wsS,
    int nb, int nTiles)
{
  // [buf][kq][row][o ^ ((row>>2 & 1)<<4)] : act reads stride-1 (free),
  // MFMA writes 2-way (free). 64 KB total.
  __shared__ __align__(16) float prered[2][8][16][64];
  __shared__ __align__(16) float lgs[2][16];

  const int tid = threadIdx.x;
  const int b   = blockIdx.x;
  const int w   = tid >> 6;        // K-slice 0..7
  const int l   = tid & 63;
  const int l15 = l & 15;          // x-row within tile / o-sub
  const int kg  = l >> 4;          // 0..3
  const int h   = tid & 31;
  const int rr  = tid >> 5;        // act row 0..15
  const int xsw = (kg & 1) << 4;          // write-side xor (kg = row>>2)
  const int xsr = ((rr >> 2) & 1) << 4;   // read-side xor

  const float vbh = Vb[h], ubh = Ub[h], wwh = ww[h];
  const float wb0 = wb[0];

  // ---- weights: B-frags for (all nt, this w): 16 x uint4 = 64 VGPR ----
  // gathered under the k-map: chunk s regs i=0..3 -> cols k0..k0+3,
  // i=4..7 -> cols k0+16..k0+19, with k0 = w*128 + s*32 + kg*4
  uint4 bfr[4][4];
  {
    #pragma unroll
    for (int nt = 0; nt < 4; ++nt) {
      const int o = (nt << 4) + l15;
      const float* Wr = (o < 32) ? (Vw + (size_t)o * NUM_IN) : (Uw + (size_t)(o - 32) * NUM_IN);
      #pragma unroll
      for (int s = 0; s < 4; ++s) {
        const int k0 = (w << 7) + (s << 5) + (kg << 2);
        const float4 a = *reinterpret_cast<const float4*>(Wr + k0);
        const float4 c = *reinterpret_cast<const float4*>(Wr + k0 + 16);
        uint4 v;
        v.x = pk2(a.x, a.y); v.y = pk2(a.z, a.w);
        v.z = pk2(c.x, c.y); v.w = pk2(c.z, c.w);
        bfr[nt][s] = v;
      }
    }
    #pragma unroll
    for (int nt = 0; nt < 4; ++nt)
      #pragma unroll
      for (int s = 0; s < 4; ++s)
        asm volatile("" : "+v"(bfr[nt][s].x), "+v"(bfr[nt][s].y),
                          "+v"(bfr[nt][s].z), "+v"(bfr[nt][s].w));
  }

  const char* xb8 = (const char*)x;
  const int inRow = (w << 9) + (kg << 4);      // byte offset within a 4 KB row

  float4 sA0[4], sB0[4], sA1[4], sB1[4];       // 64 VGPR: two staging sets
  uint4  xfA[4], xfB[4];                       // 32 VGPR: bf16 frags, 2 tiles live

  // per instruction: 16 rows x contiguous 64B -> 16 fully-consumed lines
  #define ISSUE_SET(sa, sb, Tt) do { \
    __builtin_amdgcn_sched_barrier(0); \
    const int Tc_ = ((Tt) < nTiles) ? (Tt) : (nTiles - 1); \
    const char* base_ = xb8 + ((size_t)Tc_ * TILE_R + l15) * 4096 + inRow; \
    sa[0] = *reinterpret_cast<const float4*>(base_      );  sb[0] = *reinterpret_cast<const float4*>(base_ +  64); \
    sa[1] = *reinterpret_cast<const float4*>(base_ + 128);  sb[1] = *reinterpret_cast<const float4*>(base_ + 192); \
    sa[2] = *reinterpret_cast<const float4*>(base_ + 256);  sb[2] = *reinterpret_cast<const float4*>(base_ + 320); \
    sa[3] = *reinterpret_cast<const float4*>(base_ + 384);  sb[3] = *reinterpret_cast<const float4*>(base_ + 448); \
    __builtin_amdgcn_sched_barrier(0); \
  } while (0)

  #define PACK_SET(dst, sa, sb) do { \
    _Pragma("unroll") \
    for (int s = 0; s < 4; ++s) { \
      dst[s].x = pk2(sa[s].x, sa[s].y); dst[s].y = pk2(sa[s].z, sa[s].w); \
      dst[s].z = pk2(sb[s].x, sb[s].y); dst[s].w = pk2(sb[s].z, sb[s].w); \
    } \
    _Pragma("unroll") \
    for (int s = 0; s < 4; ++s) \
      asm volatile("" : "+v"(dst[s].x), "+v"(dst[s].y), "+v"(dst[s].z), "+v"(dst[s].w)); \
  } while (0)

  float M = -INFINITY, S = 0.f;
  float acc[4][8];
  #pragma unroll
  for (int s = 0; s < 4; ++s)
    #pragma unroll
    for (int i = 0; i < 8; ++i) acc[s][i] = 0.f;

  // P1: 16 MFMAs from registers -> prered[pb]
  #define MFMA_PHASE(xfS, pb) do { \
    f32x4 a4[4] = {{0.f,0.f,0.f,0.f},{0.f,0.f,0.f,0.f},{0.f,0.f,0.f,0.f},{0.f,0.f,0.f,0.f}}; \
    _Pragma("unroll") \
    for (int s = 0; s < 4; ++s) { \
      const bf16x8 af = __builtin_bit_cast(bf16x8, xfS[s]); \
      _Pragma("unroll") \
      for (int nt = 0; nt < 4; ++nt) \
        a4[nt] = __builtin_amdgcn_mfma_f32_16x16x32_bf16( \
            af, __builtin_bit_cast(bf16x8, bfr[nt][s]), a4[nt], 0, 0, 0); \
    } \
    _Pragma("unroll") \
    for (int nt = 0; nt < 4; ++nt) \
      _Pragma("unroll") \
      for (int r = 0; r < 4; ++r) \
        prered[pb][w][(kg << 2) + r][((nt << 4) + l15) ^ xsw] = a4[nt][r]; \
  } while (0)

  // act(T): 512 threads = 16 rows x 32 h -> lgs[lb]
  #define ACT_PHASE(pb, lb) do { \
    float pv = vbh, pu = ubh; \
    _Pragma("unroll") \
    for (int q = 0; q < 8; ++q) { \
      pv += prered[pb][q][rr][h ^ xsr]; \
      pu += prered[pb][q][rr][(h + 32) ^ xsr]; \
    } \
    const float ev = __expf(2.f * pv); \
    const float av = (ev - 1.f) * __builtin_amdgcn_rcpf(ev + 1.f); \
    const float au = __builtin_amdgcn_rcpf(1.f + __expf(-pu)); \
    float g = av * au * wwh; \
    g += __shfl_xor(g, 1); \
    g += __shfl_xor(g, 2); \
    g += __shfl_xor(g, 4); \
    g += __shfl_xor(g, 8); \
    g += __shfl_xor(g, 16); \
    if (h == 0) lgs[lb][rr] = g + wb0; \
  } while (0)

  // softmax + weighted accumulation for the tile whose frags are in xfS
  #define ACC_PHASE(xfS, lb) do { \
    const float lf = lgs[lb][l15]; \
    float mc = lf; \
    mc = fmaxf(mc, __shfl_xor(mc, 1)); \
    mc = fmaxf(mc, __shfl_xor(mc, 2)); \
    mc = fmaxf(mc, __shfl_xor(mc, 4)); \
    mc = fmaxf(mc, __shfl_xor(mc, 8)); \
    if (mc > M) { \
      const float scale = __expf(M - mc); \
      S *= scale; \
      _Pragma("unroll") \
      for (int s = 0; s < 4; ++s) \
        _Pragma("unroll") \
        for (int i = 0; i < 8; ++i) acc[s][i] *= scale; \
      M = mc; \
    } \
    const float p = __expf(lf - M); \
    S += p; \
    _Pragma("unroll") \
    for (int s = 0; s < 4; ++s) { \
      acc[s][0] = fmaf(p, bflo(xfS[s].x), acc[s][0]); \
      acc[s][1] = fmaf(p, bfhi(xfS[s].x), acc[s][1]); \
      acc[s][2] = fmaf(p, bflo(xfS[s].y), acc[s][2]); \
      acc[s][3] = fmaf(p, bfhi(xfS[s].y), acc[s][3]); \
      acc[s][4] = fmaf(p, bflo(xfS[s].z), acc[s][4]); \
      acc[s][5] = fmaf(p, bfhi(xfS[s].z), acc[s][5]); \
      acc[s][6] = fmaf(p, bflo(xfS[s].w), acc[s][6]); \
      acc[s][7] = fmaf(p, bfhi(xfS[s].w), acc[s][7]); \
    } \
  } while (0)

  // ---- prologue + peeled iteration 0 (tile b, parity 0; no acc yet) ----
  ISSUE_SET(sA0, sB0, b);
  WAIT_VM(0);
  PACK_SET(xfA, sA0, sB0);             // xfA = T0
  ISSUE_SET(sA0, sB0, b + nb);         // T1
  ISSUE_SET(sA1, sB1, b + 2 * nb);     // T2
  MFMA_PHASE(xfA, 0);
  BARX();
  ACT_PHASE(0, 0);
  WAIT_VM(8);
  PACK_SET(xfB, sA0, sB0);             // xfB = T1
  ISSUE_SET(sA0, sB0, b + 3 * nb);     // T3

  int Tk = b + nb;
  int lastPar = 0;
  if (Tk < nTiles) {
    while (true) {
      // body ODD: tile Tk (parity 1): MFMA(xfB); act->lgs[1]; acc(prev, xfA, lgs[0])
      MFMA_PHASE(xfB, 1);
      BARX();
      ACT_PHASE(1, 1);
      ACC_PHASE(xfA, 0);
      WAIT_VM(8);
      PACK_SET(xfA, sA1, sB1);         // next tile (Tk+1)
      ISSUE_SET(sA1, sB1, Tk + 3 * nb);
      Tk += nb;
      if (Tk >= nTiles) { lastPar = 1; break; }

      // body EVEN: tile Tk (parity 0): MFMA(xfA); act->lgs[0]; acc(prev, xfB, lgs[1])
      MFMA_PHASE(xfA, 0);
      BARX();
      ACT_PHASE(0, 0);
      ACC_PHASE(xfB, 1);
      WAIT_VM(8);
      PACK_SET(xfB, sA0, sB0);
      ISSUE_SET(sA0, sB0, Tk + 3 * nb);
      Tk += nb;
      if (Tk >= nTiles) { lastPar = 0; break; }
    }
  }
  // drain: acc for the last tile (its act ran in the final body)
  BARX();
  if (lastPar) { ACC_PHASE(xfB, 1); } else { ACC_PHASE(xfA, 0); }

  // ---- epilogue: butterfly-sum acc & S over the 16-lane row group ----
  #pragma unroll
  for (int d = 1; d < 16; d <<= 1) {
    #pragma unroll
    for (int s = 0; s < 4; ++s)
      #pragma unroll
      for (int i = 0; i < 8; ++i) acc[s][i] += __shfl_xor(acc[s][i], d);
    S += __shfl_xor(S, d);
  }
  if (l15 == 0) {   // lane (w,kg): acc[s][0..3] -> cols k0..k0+3, [4..7] -> k0+16..+19
    #pragma unroll
    for (int s = 0; s < 4; ++s) {
      float* dst = &wsAcc[(size_t)b * NUM_IN + (w << 7) + (s << 5) + (kg << 2)];
      *reinterpret_cast<float4*>(dst)      = make_float4(acc[s][0], acc[s][1], acc[s][2], acc[s][3]);
      *reinterpret_cast<float4*>(dst + 16) = make_float4(acc[s][4], acc[s][5], acc[s][6], acc[s][7]);
    }
  }
  if (tid == 0) { wsM[b] = M; wsS[b] = S; }
}

// merged tail: 32 blocks x 256 threads. Each block redundantly reduces the
// tiny M/S arrays (2 KB, L2-resident), then computes its 32-column chunk.
__global__ void ga_tail(const float* __restrict__ wsAcc, const float* __restrict__ wsM,
                        const float* __restrict__ wsS, float* __restrict__ out, int nb)
{
  __shared__ float lwg[256];
  __shared__ float redm[4], reds[4];
  __shared__ float red[8][32];
  __shared__ float sM, sS;

  const int t = threadIdx.x;   // 256

  // global max over nb block-maxima
  float m = (t < nb) ? wsM[t] : -INFINITY;
  float mm = m;
  #pragma unroll
  for (int d = 1; d < 64; d <<= 1) mm = fmaxf(mm, __shfl_xor(mm, d));
  if ((t & 63) == 0) redm[t >> 6] = mm;
  __syncthreads();
  const float M = fmaxf(fmaxf(redm[0], redm[1]), fmaxf(redm[2], redm[3]));

  // per-block weights + total S
  const float wg = (t < nb) ? __expf(m - M) : 0.f;
  lwg[t] = wg;
  float s = wg * ((t < nb) ? wsS[t] : 0.f);
  #pragma unroll
  for (int d = 1; d < 64; d <<= 1) s += __shfl_xor(s, d);
  if ((t & 63) == 0) reds[t >> 6] = s;
  __syncthreads();
  if (t == 0) sS = reds[0] + reds[1] + reds[2] + reds[3];
  __syncthreads();

  // weighted column sum: col = bid*32 + (t&31), seg = t>>5 covers 64 i's
  const int col = (blockIdx.x << 5) + (t & 31);
  const int seg = t >> 5;
  float a = 0.f;
  #pragma unroll 4
  for (int ii = 0; ii < 64; ++ii) {
    const int i = (seg << 6) + ii;
    if (i < nb) a = fmaf(lwg[i], wsAcc[(size_t)i * NUM_IN + col], a);
  }
  red[seg][t & 31] = a;
  __syncthreads();
  if (seg == 0) {
    float tot = 0.f;
    #pragma unroll
    for (int k = 0; k < 8; ++k) tot += red[k][t];
    out[col] = tot / sS;
  }
}

extern "C" void kernel_launch(void* const* d_in, const int* in_sizes, int n_in,
                              void* d_out, int out_size, void* d_ws, size_t ws_size,
                              hipStream_t stream)
{
  const float* x  = (const float*)d_in[0];
  const float* Vw = (const float*)d_in[1];
  const float* Vb = (const float*)d_in[2];
  const float* Uw = (const float*)d_in[3];
  const float* Ub = (const float*)d_in[4];
  const float* ww = (const float*)d_in[5];
  const float* wb = (const float*)d_in[6];
  float* out = (float*)d_out;

  const int Nrows  = in_sizes[0] / NUM_IN;   // 200000
  const int nTiles = Nrows / TILE_R;         // 12500

  const size_t per = (size_t)NUM_IN * 4 + 16;
  int nb = (int)((ws_size - 64) / per);
  if (nb > NB_MAX)  nb = NB_MAX;
  if (nb > nTiles)  nb = nTiles;
  if (nb < 1)       nb = 1;

  float* wsAcc = (float*)d_ws;
  float* wsM   = wsAcc + (size_t)nb * NUM_IN;
  float* wsS   = wsM + nb;

  ga_main<<<nb, 512, 0, stream>>>(x, Vw, Uw, Vb, Ub, ww, wb, wsAcc, wsM, wsS, nb, nTiles);
  ga_tail<<<32, 256, 0, stream>>>(wsAcc, wsM, wsS, out, nb);
}